// Round 4
// baseline (233.491 us; speedup 1.0000x reference)
//
#include <hip/hip_runtime.h>
#include <math.h>

#define T_SEQ 4096
#define NBATCH 4
#define NEMBD 1024
#define HS 64
#define BT (NBATCH * T_SEQ)   // 16384

typedef float f32x4 __attribute__((ext_vector_type(4)));
typedef short s8v  __attribute__((ext_vector_type(8)));   // 8 x bf16 bits
typedef short s4v  __attribute__((ext_vector_type(4)));   // 4 x bf16 bits

__device__ __forceinline__ short f2b_rne(float f) {
    union { float f; unsigned u; } v; v.f = f;
    unsigned r = v.u + 0x7fffu + ((v.u >> 16) & 1u);
    return (short)(r >> 16);
}
// pack 2 fp32 -> 2 bf16 (truncate) in one v_perm
__device__ __forceinline__ unsigned pk2(float lo, float hi) {
    return __builtin_amdgcn_perm(__float_as_uint(hi), __float_as_uint(lo), 0x07060302u);
}

// ---------------------------------------------------------------------------
// Kernel 0a: linear cast x fp32 -> xb bf16 (HBM-friendly streaming).
// ---------------------------------------------------------------------------
__global__ __launch_bounds__(256) void xcast_kernel(
        const float* __restrict__ x, short* __restrict__ xb) {
    size_t i = ((size_t)blockIdx.x * 256 + threadIdx.x) * 16;
    float4 a = *(const float4*)(x + i);
    float4 b = *(const float4*)(x + i + 4);
    float4 c = *(const float4*)(x + i + 8);
    float4 d = *(const float4*)(x + i + 12);
    union { s8v v; unsigned u[4]; } v0, v1;
    v0.u[0] = pk2(a.x, a.y); v0.u[1] = pk2(a.z, a.w);
    v0.u[2] = pk2(b.x, b.y); v0.u[3] = pk2(b.z, b.w);
    v1.u[0] = pk2(c.x, c.y); v1.u[1] = pk2(c.z, c.w);
    v1.u[2] = pk2(d.x, d.y); v1.u[3] = pk2(d.z, d.w);
    *(s8v*)(xb + i) = v0.v;
    *(s8v*)(xb + i + 8) = v1.v;
}

// Kernel 0b (fallback if ws too small): linear touch of x to warm L3.
__global__ __launch_bounds__(256) void xtouch_kernel(
        const float* __restrict__ x, float* __restrict__ sink) {
    const float4* p = (const float4*)x;
    float s = 0.f;
    #pragma unroll
    for (int it = 0; it < 8; it++) {
        float4 v = p[(size_t)blockIdx.x * 2048 + it * 256 + threadIdx.x];
        s += v.x + v.y + v.z + v.w;
    }
    if (s == 1.0e38f) sink[0] = s;
}

// ---------------------------------------------------------------------------
// Kernel 1: W{q,k,v} [1024x64] fp32 -> Wt[192][1024] bf16 transposed.
// Softmax scale C^-0.5 * log2(e) folded into Wq.
// ---------------------------------------------------------------------------
__global__ __launch_bounds__(256) void wtrans_kernel(
        const float* __restrict__ Wq, const float* __restrict__ Wk,
        const float* __restrict__ Wv, short* __restrict__ Wt) {
    int e = blockIdx.x * 256 + threadIdx.x;
    int col = e & 63, k = (e >> 6) & 1023, mat = e >> 16;
    const float* W = (mat == 0) ? Wq : ((mat == 1) ? Wk : Wv);
    float scale = (mat == 0) ? 0.0450842298f : 1.0f;   // 2^-5 * log2(e)
    Wt[(size_t)(mat * 64 + col) * 1024 + k] = f2b_rne(W[k * 64 + col] * scale);
}

// ---------------------------------------------------------------------------
// Kernel 2: projections v3 (unchanged from R7).
// ---------------------------------------------------------------------------
template<bool SRC_BF16>
__global__ __launch_bounds__(512) void proj_kernel(
        const void* __restrict__ xsrc, const short* __restrict__ Wt,
        short* __restrict__ QKV) {
    __shared__ short xs[32 * 72];
    __shared__ short wsh[192 * 72];
    int tid = threadIdx.x;
    int w = tid >> 6, l = tid & 63, quad = l >> 4, c16 = l & 15;
    int rt = w >> 2, cg = w & 3;
    int row0 = blockIdx.x * 32;
    short* VpT = QKV + 2 * (size_t)BT * HS;   // tiled [b][kt][64 d][64 key]

    const short* xb = (const short*)xsrc;
    const float* xf = (const float*)xsrc;
    int xrow_b = tid >> 3,  xc8 = (tid & 7) * 8;
    int xrow_f = tid >> 4,  xc4 = (tid & 15) * 4;

    s8v  wreg[3];
    s8v  xreg_b;
    float4 xreg_f;
    #pragma unroll
    for (int i = 0; i < 3; i++) {
        int c = tid + 512 * i;
        wreg[i] = *(const s8v*)(Wt + (size_t)(c >> 3) * 1024 + ((c & 7) * 8));
    }
    if (SRC_BF16) {
        if (tid < 256) xreg_b = *(const s8v*)(xb + (size_t)(row0 + xrow_b) * 1024 + xc8);
    } else {
        xreg_f = *(const float4*)(xf + (size_t)(row0 + xrow_f) * 1024 + xc4);
    }

    f32x4 acc[3] = {};
    for (int ko = 0; ko < NEMBD; ko += 64) {
        #pragma unroll
        for (int i = 0; i < 3; i++) {
            int c = tid + 512 * i;
            *(s8v*)(wsh + (c >> 3) * 72 + ((c & 7) * 8)) = wreg[i];
        }
        if (SRC_BF16) {
            if (tid < 256) *(s8v*)(xs + xrow_b * 72 + xc8) = xreg_b;
        } else {
            union { s4v v; unsigned u[2]; } pkv;
            pkv.u[0] = pk2(xreg_f.x, xreg_f.y);
            pkv.u[1] = pk2(xreg_f.z, xreg_f.w);
            *(s4v*)(xs + xrow_f * 72 + xc4) = pkv.v;
        }
        __syncthreads();
        {
            int kn = (ko + 64 < NEMBD) ? (ko + 64) : 0;
            #pragma unroll
            for (int i = 0; i < 3; i++) {
                int c = tid + 512 * i;
                wreg[i] = *(const s8v*)(Wt + (size_t)(c >> 3) * 1024 + kn + ((c & 7) * 8));
            }
            if (SRC_BF16) {
                if (tid < 256) xreg_b = *(const s8v*)(xb + (size_t)(row0 + xrow_b) * 1024 + kn + xc8);
            } else {
                xreg_f = *(const float4*)(xf + (size_t)(row0 + xrow_f) * 1024 + kn + xc4);
            }
        }
        #pragma unroll
        for (int ks = 0; ks < 2; ks++) {
            s8v a = *(const s8v*)(xs + (rt * 16 + c16) * 72 + ks * 32 + quad * 8);
            #pragma unroll
            for (int j = 0; j < 3; j++) {
                s8v b = *(const s8v*)(wsh + (cg * 48 + j * 16 + c16) * 72 + ks * 32 + quad * 8);
                acc[j] = __builtin_amdgcn_mfma_f32_16x16x32_bf16(a, b, acc[j], 0, 0, 0);
            }
        }
        __syncthreads();
    }
    #pragma unroll
    for (int j = 0; j < 3; j++) {
        int g = cg * 48 + j * 16 + c16;
        int mat = g >> 6, h = g & 63;
        if (mat < 2) {
            #pragma unroll
            for (int r = 0; r < 4; r++) {
                int row = row0 + rt * 16 + quad * 4 + r;
                QKV[(size_t)mat * BT * HS + (size_t)row * HS + h] = f2b_rne(acc[j][r]);
            }
        } else {
            int tg = row0 + rt * 16 + quad * 4;
            int b = tg >> 12, t = tg & 4095;
            size_t base = (((size_t)((b * 64 + (t >> 6)) * 64 + h)) << 6) + (t & 63);
            s4v pv;
            #pragma unroll
            for (int r = 0; r < 4; r++) pv[r] = f2b_rne(acc[j][r]);
            *(s4v*)(VpT + base) = pv;
        }
    }
}

// ---------------------------------------------------------------------------
// Kernel 3: causal flash attention — R14 = R13 resubmitted verbatim (the R3
// bench died with "container failed twice" and no compile/test error; code
// audit found no OOB/deadlock/resource violation -> infra flake assumed).
// Design ("fused pair"):
//  * Tile body = R10 verbatim (no cross-tile K prefetch: R9/R12 proved it
//    spills ~150MB scratch at the 128-VGPR cap).
//  * ONE 1024-thread block (16 waves) per CU owns the q-tile PAIR
//    (jtA=m, jtB=127-m); nktA+nktB == 65 for every m -> identical work per
//    block; waves stride the combined 65-tile list (4-5 tiles each, all
//    busy until the end; R10 averaged ~9.5/16 waves alive).
//  * per-wave partials merge in LDS via ds_add_f32 (no HBM partials —
//    R11's mistake).
//  * XCD-affine: batch = bi&3 (2MB K+V resident per XCD L2).
// LDS: 73.7KB P + 16.4KB oacc + 256B lacc ~= 90KB, 1 block/CU.
// ---------------------------------------------------------------------------
__global__ __launch_bounds__(1024, 4) void attn_kernel(
        const short* __restrict__ QKV, float* __restrict__ out) {
    __shared__ short Ps[16 * 2 * 1152];   // 73728 B: per-wave P regions
    __shared__ float oacc[2 * 32 * 64];   // 16384 B: pair output accum
    __shared__ float lacc[64];            // 2 x 32 row denominators

    int tid = threadIdx.x;
    int w = tid >> 6, l = tid & 63, quad = l >> 4, c16 = l & 15;
    int bi = blockIdx.x;
    int b  = bi & 3;                      // XCD-affine batch (XCD = bi&7)
    int m  = bi >> 2;                     // 0..63
    int jtA = m, jtB = 127 - m;
    int nktA = (jtA >> 1) + 1;
    int nktB = (jtB >> 1) + 1;            // nktA + nktB == 65

    const short* Qp  = QKV;
    const short* Kp  = QKV + (size_t)BT * HS;
    const short* VpT = QKV + 2 * (size_t)BT * HS;   // tiled
    size_t bT = (size_t)b * T_SEQ;

    // zero the LDS accumulators
    *(f32x4*)&oacc[tid * 4] = (f32x4){0.f, 0.f, 0.f, 0.f};
    if (tid < 64) lacc[tid] = 0.f;
    __syncthreads();

    const short* kbase = Kp + (bT + c16) * HS + quad * 8;
    const short* vbase = VpT + (((size_t)((b * 64) * 64 + c16)) << 6) + quad * 8;
    short* Pw[2] = { Ps + (w * 2) * 1152, Ps + (w * 2 + 1) * 1152 };

    s8v qf[2][2];
    f32x4 o[2][4] = {};
    float lsA[2] = {0.f, 0.f}, lsB[2] = {0.f, 0.f};

    auto load_q = [&](int q0) {
        #pragma unroll
        for (int qt = 0; qt < 2; qt++)
            #pragma unroll
            for (int h = 0; h < 2; h++)
                qf[qt][h] = *(const s8v*)(Qp + (bT + q0 + qt * 16 + c16) * HS + h * 32 + quad * 8);
    };

    auto tile = [&](int kt, int q0, bool last) {
        int kb = kt * 64;
        // phase 1: all K fragment loads (one wait)
        s8v kf[4][2];
        #pragma unroll
        for (int nt = 0; nt < 4; nt++) {
            const short* kr = kbase + (size_t)(kb + nt * 16) * HS;
            kf[nt][0] = *(const s8v*)kr;
            kf[nt][1] = *(const s8v*)(kr + 32);
        }
        // phase 2: S^T = K * Q^T
        f32x4 st[2][4];
        __builtin_amdgcn_s_setprio(1);
        #pragma unroll
        for (int nt = 0; nt < 4; nt++) {
            f32x4 z0 = {0.f, 0.f, 0.f, 0.f}, z1 = {0.f, 0.f, 0.f, 0.f};
            z0 = __builtin_amdgcn_mfma_f32_16x16x32_bf16(kf[nt][0], qf[0][0], z0, 0, 0, 0);
            z0 = __builtin_amdgcn_mfma_f32_16x16x32_bf16(kf[nt][1], qf[0][1], z0, 0, 0, 0);
            z1 = __builtin_amdgcn_mfma_f32_16x16x32_bf16(kf[nt][0], qf[1][0], z1, 0, 0, 0);
            z1 = __builtin_amdgcn_mfma_f32_16x16x32_bf16(kf[nt][1], qf[1][1], z1, 0, 0, 0);
            st[0][nt] = z0; st[1][nt] = z1;
        }
        __builtin_amdgcn_s_setprio(0);
        // phase 3: all V fragment loads (hidden by softmax)
        s8v vf[4][2];
        #pragma unroll
        for (int nt = 0; nt < 4; nt++) {
            const short* vr = vbase + (((size_t)(kb + nt * 16)) << 6);
            vf[nt][0] = *(const s8v*)vr;
            vf[nt][1] = *(const s8v*)(vr + 32);
        }
        // phase 4: exp2, diag mask, lsum, pack P -> LDS
        #pragma unroll
        for (int qt = 0; qt < 2; qt++) {
            int qrow = q0 + qt * 16 + c16;
            #pragma unroll
            for (int nt = 0; nt < 4; nt++) {
                float pr[4];
                #pragma unroll
                for (int rr = 0; rr < 4; rr++) {
                    float v = st[qt][nt][rr];
                    if (last && (kb + nt * 16 + quad * 4 + rr > qrow)) v = -30000.f;
                    pr[rr] = __builtin_amdgcn_exp2f(v);
                }
                lsA[qt] += pr[0] + pr[1];
                lsB[qt] += pr[2] + pr[3];
                union { s4v v; unsigned u[2]; } pkv;
                pkv.u[0] = pk2(pr[0], pr[1]); pkv.u[1] = pk2(pr[2], pr[3]);
                *(s4v*)(Pw[qt] + c16 * 72 + nt * 16 + quad * 4) = pkv.v;
            }
        }
        // phase 5: P A-frags; phase 6: PV MFMAs
        s8v pa[2][2];
        #pragma unroll
        for (int qt = 0; qt < 2; qt++) {
            pa[qt][0] = *(const s8v*)(Pw[qt] + c16 * 72 + quad * 8);
            pa[qt][1] = *(const s8v*)(Pw[qt] + c16 * 72 + quad * 8 + 32);
        }
        __builtin_amdgcn_s_setprio(1);
        #pragma unroll
        for (int nt = 0; nt < 4; nt++)
            #pragma unroll
            for (int qt = 0; qt < 2; qt++) {
                o[qt][nt] = __builtin_amdgcn_mfma_f32_16x16x32_bf16(pa[qt][0], vf[nt][0], o[qt][nt], 0, 0, 0);
                o[qt][nt] = __builtin_amdgcn_mfma_f32_16x16x32_bf16(pa[qt][1], vf[nt][1], o[qt][nt], 0, 0, 0);
            }
        __builtin_amdgcn_s_setprio(0);
    };

    auto flush = [&](int sel) {
        float ls0 = lsA[0] + lsB[0];
        float ls1 = lsA[1] + lsB[1];
        ls0 += __shfl_xor(ls0, 16); ls0 += __shfl_xor(ls0, 32);
        ls1 += __shfl_xor(ls1, 16); ls1 += __shfl_xor(ls1, 32);
        if (l < 16) {
            atomicAdd(&lacc[sel * 32 + l], ls0);
            atomicAdd(&lacc[sel * 32 + 16 + l], ls1);
        }
        #pragma unroll
        for (int qt = 0; qt < 2; qt++)
            #pragma unroll
            for (int nt = 0; nt < 4; nt++)
                #pragma unroll
                for (int rr = 0; rr < 4; rr++)
                    atomicAdd(&oacc[sel * 2048 + (qt * 16 + quad * 4 + rr) * 64 + nt * 16 + c16],
                              o[qt][nt][rr]);
        #pragma unroll
        for (int qt = 0; qt < 2; qt++) {
            o[qt][0] = (f32x4){0.f, 0.f, 0.f, 0.f};
            o[qt][1] = (f32x4){0.f, 0.f, 0.f, 0.f};
            o[qt][2] = (f32x4){0.f, 0.f, 0.f, 0.f};
            o[qt][3] = (f32x4){0.f, 0.f, 0.f, 0.f};
            lsA[qt] = 0.f; lsB[qt] = 0.f;
        }
    };

    // ---- segment A: tiles g in [0, nktA), this wave's subset ----
    if (w < nktA) {
        load_q(jtA * 32);
        for (int kt = w; kt < nktA; kt += 16)
            tile(kt, jtA * 32, kt == nktA - 1);
        flush(0);
    }
    // ---- segment B: tiles g in [nktA, 65), this wave's subset ----
    {
        int i0 = (nktA > w) ? ((nktA - w + 15) >> 4) : 0;
        int g0 = w + (i0 << 4);
        if (g0 < 65) {
            load_q(jtB * 32);
            for (int g = g0; g < 65; g += 16) {
                int kt = g - nktA;
                tile(kt, jtB * 32, kt == nktB - 1);
            }
            flush(1);
        }
    }

    __syncthreads();
    // ---- epilogue: divide and write both q-tiles (16 KB, coalesced) ----
    {
        int sel = tid >> 9, rem = tid & 511;
        int row = rem >> 4, c4 = (rem & 15) << 2;
        int jt  = sel ? jtB : jtA;
        f32x4 ov = *(const f32x4*)&oacc[sel * 2048 + row * 64 + c4];
        float inv = 1.0f / lacc[sel * 32 + row];
        *(f32x4*)(out + (bT + (size_t)(jt * 32 + row)) * HS + c4) = ov * inv;
    }
}

// ---------------------------------------------------------------------------
extern "C" void kernel_launch(void* const* d_in, const int* in_sizes, int n_in,
                              void* d_out, int out_size, void* d_ws, size_t ws_size,
                              hipStream_t stream) {
    const float* x  = (const float*)d_in[0];
    const float* Wq = (const float*)d_in[1];
    const float* Wk = (const float*)d_in[2];
    const float* Wv = (const float*)d_in[3];
    float* out = (float*)d_out;

    short* QKV = (short*)d_ws;
    short* Wt  = QKV + (size_t)3 * BT * HS;
    short* xb  = Wt + (size_t)192 * 1024;
    size_t need = ((size_t)3 * BT * HS + (size_t)192 * 1024 + (size_t)BT * NEMBD) * 2;

    wtrans_kernel<<<768, 256, 0, stream>>>(Wq, Wk, Wv, Wt);
    if (ws_size >= need) {
        xcast_kernel<<<4096, 256, 0, stream>>>(x, xb);
        proj_kernel<true><<<BT / 32, 512, 0, stream>>>(xb, Wt, QKV);
    } else {
        xtouch_kernel<<<2048, 256, 0, stream>>>(x, (float*)d_ws);
        proj_kernel<false><<<BT / 32, 512, 0, stream>>>(x, Wt, QKV);
    }
    attn_kernel<<<256, 1024, 0, stream>>>(QKV, out);
}

// Round 5
// 231.321 us; speedup vs baseline: 1.0094x; 1.0094x over previous
//
#include <hip/hip_runtime.h>
#include <math.h>

#define T_SEQ 4096
#define NBATCH 4
#define NEMBD 1024
#define HS 64
#define BT (NBATCH * T_SEQ)   // 16384

typedef float f32x4 __attribute__((ext_vector_type(4)));
typedef short s8v  __attribute__((ext_vector_type(8)));   // 8 x bf16 bits
typedef short s4v  __attribute__((ext_vector_type(4)));   // 4 x bf16 bits

__device__ __forceinline__ short f2b_rne(float f) {
    union { float f; unsigned u; } v; v.f = f;
    unsigned r = v.u + 0x7fffu + ((v.u >> 16) & 1u);
    return (short)(r >> 16);
}
// pack 2 fp32 -> 2 bf16 (truncate) in one v_perm
__device__ __forceinline__ unsigned pk2(float lo, float hi) {
    return __builtin_amdgcn_perm(__float_as_uint(hi), __float_as_uint(lo), 0x07060302u);
}

// ---------------------------------------------------------------------------
// Kernel 0a: linear cast x fp32 -> xb bf16 (HBM-friendly streaming).
// ---------------------------------------------------------------------------
__global__ __launch_bounds__(256) void xcast_kernel(
        const float* __restrict__ x, short* __restrict__ xb) {
    size_t i = ((size_t)blockIdx.x * 256 + threadIdx.x) * 16;
    float4 a = *(const float4*)(x + i);
    float4 b = *(const float4*)(x + i + 4);
    float4 c = *(const float4*)(x + i + 8);
    float4 d = *(const float4*)(x + i + 12);
    union { s8v v; unsigned u[4]; } v0, v1;
    v0.u[0] = pk2(a.x, a.y); v0.u[1] = pk2(a.z, a.w);
    v0.u[2] = pk2(b.x, b.y); v0.u[3] = pk2(b.z, b.w);
    v1.u[0] = pk2(c.x, c.y); v1.u[1] = pk2(c.z, c.w);
    v1.u[2] = pk2(d.x, d.y); v1.u[3] = pk2(d.z, d.w);
    *(s8v*)(xb + i) = v0.v;
    *(s8v*)(xb + i + 8) = v1.v;
}

// Kernel 0b (fallback if ws too small): linear touch of x to warm L3.
__global__ __launch_bounds__(256) void xtouch_kernel(
        const float* __restrict__ x, float* __restrict__ sink) {
    const float4* p = (const float4*)x;
    float s = 0.f;
    #pragma unroll
    for (int it = 0; it < 8; it++) {
        float4 v = p[(size_t)blockIdx.x * 2048 + it * 256 + threadIdx.x];
        s += v.x + v.y + v.z + v.w;
    }
    if (s == 1.0e38f) sink[0] = s;
}

// ---------------------------------------------------------------------------
// Kernel 1: W{q,k,v} [1024x64] fp32 -> Wt[192][1024] bf16 transposed.
// Softmax scale C^-0.5 * log2(e) folded into Wq.
// ---------------------------------------------------------------------------
__global__ __launch_bounds__(256) void wtrans_kernel(
        const float* __restrict__ Wq, const float* __restrict__ Wk,
        const float* __restrict__ Wv, short* __restrict__ Wt) {
    int e = blockIdx.x * 256 + threadIdx.x;
    int col = e & 63, k = (e >> 6) & 1023, mat = e >> 16;
    const float* W = (mat == 0) ? Wq : ((mat == 1) ? Wk : Wv);
    float scale = (mat == 0) ? 0.0450842298f : 1.0f;   // 2^-5 * log2(e)
    Wt[(size_t)(mat * 64 + col) * 1024 + k] = f2b_rne(W[k * 64 + col] * scale);
}

// ---------------------------------------------------------------------------
// Kernel 2: projections v3 (unchanged from R7).
// ---------------------------------------------------------------------------
template<bool SRC_BF16>
__global__ __launch_bounds__(512) void proj_kernel(
        const void* __restrict__ xsrc, const short* __restrict__ Wt,
        short* __restrict__ QKV) {
    __shared__ short xs[32 * 72];
    __shared__ short wsh[192 * 72];
    int tid = threadIdx.x;
    int w = tid >> 6, l = tid & 63, quad = l >> 4, c16 = l & 15;
    int rt = w >> 2, cg = w & 3;
    int row0 = blockIdx.x * 32;
    short* VpT = QKV + 2 * (size_t)BT * HS;   // tiled [b][kt][64 d][64 key]

    const short* xb = (const short*)xsrc;
    const float* xf = (const float*)xsrc;
    int xrow_b = tid >> 3,  xc8 = (tid & 7) * 8;
    int xrow_f = tid >> 4,  xc4 = (tid & 15) * 4;

    s8v  wreg[3];
    s8v  xreg_b;
    float4 xreg_f;
    #pragma unroll
    for (int i = 0; i < 3; i++) {
        int c = tid + 512 * i;
        wreg[i] = *(const s8v*)(Wt + (size_t)(c >> 3) * 1024 + ((c & 7) * 8));
    }
    if (SRC_BF16) {
        if (tid < 256) xreg_b = *(const s8v*)(xb + (size_t)(row0 + xrow_b) * 1024 + xc8);
    } else {
        xreg_f = *(const float4*)(xf + (size_t)(row0 + xrow_f) * 1024 + xc4);
    }

    f32x4 acc[3] = {};
    for (int ko = 0; ko < NEMBD; ko += 64) {
        #pragma unroll
        for (int i = 0; i < 3; i++) {
            int c = tid + 512 * i;
            *(s8v*)(wsh + (c >> 3) * 72 + ((c & 7) * 8)) = wreg[i];
        }
        if (SRC_BF16) {
            if (tid < 256) *(s8v*)(xs + xrow_b * 72 + xc8) = xreg_b;
        } else {
            union { s4v v; unsigned u[2]; } pkv;
            pkv.u[0] = pk2(xreg_f.x, xreg_f.y);
            pkv.u[1] = pk2(xreg_f.z, xreg_f.w);
            *(s4v*)(xs + xrow_f * 72 + xc4) = pkv.v;
        }
        __syncthreads();
        {
            int kn = (ko + 64 < NEMBD) ? (ko + 64) : 0;
            #pragma unroll
            for (int i = 0; i < 3; i++) {
                int c = tid + 512 * i;
                wreg[i] = *(const s8v*)(Wt + (size_t)(c >> 3) * 1024 + kn + ((c & 7) * 8));
            }
            if (SRC_BF16) {
                if (tid < 256) xreg_b = *(const s8v*)(xb + (size_t)(row0 + xrow_b) * 1024 + kn + xc8);
            } else {
                xreg_f = *(const float4*)(xf + (size_t)(row0 + xrow_f) * 1024 + kn + xc4);
            }
        }
        #pragma unroll
        for (int ks = 0; ks < 2; ks++) {
            s8v a = *(const s8v*)(xs + (rt * 16 + c16) * 72 + ks * 32 + quad * 8);
            #pragma unroll
            for (int j = 0; j < 3; j++) {
                s8v b = *(const s8v*)(wsh + (cg * 48 + j * 16 + c16) * 72 + ks * 32 + quad * 8);
                acc[j] = __builtin_amdgcn_mfma_f32_16x16x32_bf16(a, b, acc[j], 0, 0, 0);
            }
        }
        __syncthreads();
    }
    #pragma unroll
    for (int j = 0; j < 3; j++) {
        int g = cg * 48 + j * 16 + c16;
        int mat = g >> 6, h = g & 63;
        if (mat < 2) {
            #pragma unroll
            for (int r = 0; r < 4; r++) {
                int row = row0 + rt * 16 + quad * 4 + r;
                QKV[(size_t)mat * BT * HS + (size_t)row * HS + h] = f2b_rne(acc[j][r]);
            }
        } else {
            int tg = row0 + rt * 16 + quad * 4;
            int b = tg >> 12, t = tg & 4095;
            size_t base = (((size_t)((b * 64 + (t >> 6)) * 64 + h)) << 6) + (t & 63);
            s4v pv;
            #pragma unroll
            for (int r = 0; r < 4; r++) pv[r] = f2b_rne(acc[j][r]);
            *(s4v*)(VpT + base) = pv;
        }
    }
}

// ---------------------------------------------------------------------------
// Kernel 3: causal flash attention — R15 "wide blocks".
// Tile body = R10 VERBATIM (64 VGPR, no barriers in main loop, no cross-tile
// prefetch — R9/R12/R13 all spilled).  Single structural change:
//  * 16 waves per block (1024 threads), kt stride 16, same grid mapping
//    (512 blocks, 1 per (b, q-tile), big-jt blocks dispatched first).
//    R10 capped residency at 2 blocks x 8 waves = 4/SIMD, dropping to
//    2/SIMD once the small partner block retired (measured 29% occupancy,
//    latency-bound: both pipes <15%).  Same LDS/VGPR footprint per wave ->
//    2 blocks/CU resident = 8 waves/SIMD at start.
//  * __launch_bounds__(1024, 8) pins the VGPR cap at 64 (the body already
//    compiles to exactly 64; any spill shows as WRITE_SIZE >> 10MB).
//  * epilogue: R10's two-phase smem merge widened to 16 waves (o-region
//    64KB overlays P-regions; lsum at float offset 16384).
// LDS: 73728 B.  2 blocks/CU = 144KB <= 160KB.
// ---------------------------------------------------------------------------
__global__ __launch_bounds__(1024, 8) void attn_kernel(
        const short* __restrict__ QKV, float* __restrict__ out) {
    __shared__ float smem[18432];   // 72 KB: 16x2 P regions; epilogue overlays
    short* Ps = (short*)smem;

    int tid = threadIdx.x;
    int w = tid >> 6, l = tid & 63, quad = l >> 4, c16 = l & 15;
    int bi = blockIdx.x;
    int b  = (bi & 7) >> 1;                 // XCD-affine batch
    int r8 = bi >> 3;                       // 0..63
    int p  = bi & 1;
    int jt = (r8 < 32) ? (127 - (2 * r8 + p)) : (2 * (r8 - 32) + p);
    int q0 = jt * 32;

    const short* Qp  = QKV;
    const short* Kp  = QKV + (size_t)BT * HS;
    const short* VpT = QKV + 2 * (size_t)BT * HS;   // tiled
    size_t bT = (size_t)b * T_SEQ;

    s8v qf[2][2];
    #pragma unroll
    for (int qt = 0; qt < 2; qt++)
        #pragma unroll
        for (int h = 0; h < 2; h++)
            qf[qt][h] = *(const s8v*)(Qp + (bT + q0 + qt * 16 + c16) * HS + h * 32 + quad * 8);

    f32x4 o[2][4] = {};
    float lsA[2] = {0.f, 0.f}, lsB[2] = {0.f, 0.f};
    int nkt = (q0 >> 6) + 1;
    short* Pw[2] = { Ps + (w * 2) * 1152, Ps + (w * 2 + 1) * 1152 };
    const short* kbase = Kp + (bT + c16) * HS + quad * 8;
    const short* vbase = VpT + (((size_t)((b * 64) * 64 + c16)) << 6) + quad * 8;

    for (int kt = w; kt < nkt; kt += 16) {
        int kb = kt * 64;
        bool last = (kt == nkt - 1);

        // ---- phase 1: issue ALL K fragment loads (8 x b128, one wait) ----
        s8v kf[4][2];
        #pragma unroll
        for (int nt = 0; nt < 4; nt++) {
            const short* kr = kbase + (size_t)(kb + nt * 16) * HS;
            kf[nt][0] = *(const s8v*)kr;
            kf[nt][1] = *(const s8v*)(kr + 32);
        }
        // ---- phase 2: S^T = K * Q^T ----
        f32x4 st[2][4];
        __builtin_amdgcn_s_setprio(1);
        #pragma unroll
        for (int nt = 0; nt < 4; nt++) {
            f32x4 z0 = {0.f, 0.f, 0.f, 0.f}, z1 = {0.f, 0.f, 0.f, 0.f};
            z0 = __builtin_amdgcn_mfma_f32_16x16x32_bf16(kf[nt][0], qf[0][0], z0, 0, 0, 0);
            z0 = __builtin_amdgcn_mfma_f32_16x16x32_bf16(kf[nt][1], qf[0][1], z0, 0, 0, 0);
            z1 = __builtin_amdgcn_mfma_f32_16x16x32_bf16(kf[nt][0], qf[1][0], z1, 0, 0, 0);
            z1 = __builtin_amdgcn_mfma_f32_16x16x32_bf16(kf[nt][1], qf[1][1], z1, 0, 0, 0);
            st[0][nt] = z0; st[1][nt] = z1;
        }
        __builtin_amdgcn_s_setprio(0);
        // ---- phase 3: issue ALL V fragment loads (hidden by softmax) ----
        s8v vf[4][2];
        #pragma unroll
        for (int nt = 0; nt < 4; nt++) {
            const short* vr = vbase + (((size_t)(kb + nt * 16)) << 6);
            vf[nt][0] = *(const s8v*)vr;
            vf[nt][1] = *(const s8v*)(vr + 32);
        }
        // ---- phase 4: exp2, diag mask, lsum, pack P -> LDS ----
        #pragma unroll
        for (int qt = 0; qt < 2; qt++) {
            int qrow = q0 + qt * 16 + c16;
            #pragma unroll
            for (int nt = 0; nt < 4; nt++) {
                float pr[4];
                #pragma unroll
                for (int rr = 0; rr < 4; rr++) {
                    float v = st[qt][nt][rr];
                    if (last && (kb + nt * 16 + quad * 4 + rr > qrow)) v = -30000.f;
                    pr[rr] = __builtin_amdgcn_exp2f(v);
                }
                lsA[qt] += pr[0] + pr[1];
                lsB[qt] += pr[2] + pr[3];
                union { s4v v; unsigned u[2]; } pkv;
                pkv.u[0] = pk2(pr[0], pr[1]); pkv.u[1] = pk2(pr[2], pr[3]);
                *(s4v*)(Pw[qt] + c16 * 72 + nt * 16 + quad * 4) = pkv.v;
            }
        }
        // ---- phase 5: P A-frags from LDS; phase 6: PV MFMAs ----
        s8v pa[2][2];
        #pragma unroll
        for (int qt = 0; qt < 2; qt++) {
            pa[qt][0] = *(const s8v*)(Pw[qt] + c16 * 72 + quad * 8);
            pa[qt][1] = *(const s8v*)(Pw[qt] + c16 * 72 + quad * 8 + 32);
        }
        __builtin_amdgcn_s_setprio(1);
        #pragma unroll
        for (int nt = 0; nt < 4; nt++)
            #pragma unroll
            for (int qt = 0; qt < 2; qt++) {
                o[qt][nt] = __builtin_amdgcn_mfma_f32_16x16x32_bf16(pa[qt][0], vf[nt][0], o[qt][nt], 0, 0, 0);
                o[qt][nt] = __builtin_amdgcn_mfma_f32_16x16x32_bf16(pa[qt][1], vf[nt][1], o[qt][nt], 0, 0, 0);
            }
        __builtin_amdgcn_s_setprio(0);
    }

    float lsum[2] = { lsA[0] + lsB[0], lsA[1] + lsB[1] };
    #pragma unroll
    for (int qt = 0; qt < 2; qt++) {
        lsum[qt] += __shfl_xor(lsum[qt], 16);
        lsum[qt] += __shfl_xor(lsum[qt], 32);
    }

    // two-phase per-lane merge across 16 waves (R5 structure, widened)
    #pragma unroll
    for (int qt = 0; qt < 2; qt++) {
        __syncthreads();
        #pragma unroll
        for (int nt = 0; nt < 4; nt++)
            *(f32x4*)(smem + ((w * 4 + nt) * 64 + l) * 4) = o[qt][nt];
        if (l < 16) smem[16384 + w * 16 + l] = lsum[qt];
        __syncthreads();
        if (w < 4) {
            f32x4 os = {0.f, 0.f, 0.f, 0.f}, ls = {0.f, 0.f, 0.f, 0.f};
            #pragma unroll
            for (int s = 0; s < 16; s++) {
                os += *(const f32x4*)(smem + ((s * 4 + w) * 64 + l) * 4);
                ls += *(const f32x4*)(smem + 16384 + s * 16 + quad * 4);
            }
            #pragma unroll
            for (int rr = 0; rr < 4; rr++)
                out[(bT + q0 + qt * 16 + quad * 4 + rr) * HS + w * 16 + c16] = os[rr] / ls[rr];
        }
    }
}

// ---------------------------------------------------------------------------
extern "C" void kernel_launch(void* const* d_in, const int* in_sizes, int n_in,
                              void* d_out, int out_size, void* d_ws, size_t ws_size,
                              hipStream_t stream) {
    const float* x  = (const float*)d_in[0];
    const float* Wq = (const float*)d_in[1];
    const float* Wk = (const float*)d_in[2];
    const float* Wv = (const float*)d_in[3];
    float* out = (float*)d_out;

    short* QKV = (short*)d_ws;
    short* Wt  = QKV + (size_t)3 * BT * HS;
    short* xb  = Wt + (size_t)192 * 1024;
    size_t need = ((size_t)3 * BT * HS + (size_t)192 * 1024 + (size_t)BT * NEMBD) * 2;

    wtrans_kernel<<<768, 256, 0, stream>>>(Wq, Wk, Wv, Wt);
    if (ws_size >= need) {
        xcast_kernel<<<4096, 256, 0, stream>>>(x, xb);
        proj_kernel<true><<<BT / 32, 512, 0, stream>>>(xb, Wt, QKV);
    } else {
        xtouch_kernel<<<2048, 256, 0, stream>>>(x, (float*)d_ws);
        proj_kernel<false><<<BT / 32, 512, 0, stream>>>(x, Wt, QKV);
    }
    attn_kernel<<<512, 1024, 0, stream>>>(QKV, out);
}

// Round 6
// 195.686 us; speedup vs baseline: 1.1932x; 1.1821x over previous
//
#include <hip/hip_runtime.h>
#include <math.h>

#define T_SEQ 4096
#define NBATCH 4
#define NEMBD 1024
#define HS 64
#define BT (NBATCH * T_SEQ)   // 16384

typedef float f32x4 __attribute__((ext_vector_type(4)));
typedef short s8v  __attribute__((ext_vector_type(8)));   // 8 x bf16 bits
typedef short s4v  __attribute__((ext_vector_type(4)));   // 4 x bf16 bits

__device__ __forceinline__ short f2b_rne(float f) {
    union { float f; unsigned u; } v; v.f = f;
    unsigned r = v.u + 0x7fffu + ((v.u >> 16) & 1u);
    return (short)(r >> 16);
}
// pack 2 fp32 -> 2 bf16 (truncate) in one v_perm
__device__ __forceinline__ unsigned pk2(float lo, float hi) {
    return __builtin_amdgcn_perm(__float_as_uint(hi), __float_as_uint(lo), 0x07060302u);
}

// ---------------------------------------------------------------------------
// Kernel 0a: linear cast x fp32 -> xb bf16 (HBM-friendly streaming).
// ---------------------------------------------------------------------------
__global__ __launch_bounds__(256) void xcast_kernel(
        const float* __restrict__ x, short* __restrict__ xb) {
    size_t i = ((size_t)blockIdx.x * 256 + threadIdx.x) * 16;
    float4 a = *(const float4*)(x + i);
    float4 b = *(const float4*)(x + i + 4);
    float4 c = *(const float4*)(x + i + 8);
    float4 d = *(const float4*)(x + i + 12);
    union { s8v v; unsigned u[4]; } v0, v1;
    v0.u[0] = pk2(a.x, a.y); v0.u[1] = pk2(a.z, a.w);
    v0.u[2] = pk2(b.x, b.y); v0.u[3] = pk2(b.z, b.w);
    v1.u[0] = pk2(c.x, c.y); v1.u[1] = pk2(c.z, c.w);
    v1.u[2] = pk2(d.x, d.y); v1.u[3] = pk2(d.z, d.w);
    *(s8v*)(xb + i) = v0.v;
    *(s8v*)(xb + i + 8) = v1.v;
}

// Kernel 0b (fallback if ws too small): linear touch of x to warm L3.
__global__ __launch_bounds__(256) void xtouch_kernel(
        const float* __restrict__ x, float* __restrict__ sink) {
    const float4* p = (const float4*)x;
    float s = 0.f;
    #pragma unroll
    for (int it = 0; it < 8; it++) {
        float4 v = p[(size_t)blockIdx.x * 2048 + it * 256 + threadIdx.x];
        s += v.x + v.y + v.z + v.w;
    }
    if (s == 1.0e38f) sink[0] = s;
}

// ---------------------------------------------------------------------------
// Kernel 1: W{q,k,v} [1024x64] fp32 -> Wt[192][1024] bf16 transposed.
// Softmax scale C^-0.5 * log2(e) folded into Wq.
// ---------------------------------------------------------------------------
__global__ __launch_bounds__(256) void wtrans_kernel(
        const float* __restrict__ Wq, const float* __restrict__ Wk,
        const float* __restrict__ Wv, short* __restrict__ Wt) {
    int e = blockIdx.x * 256 + threadIdx.x;
    int col = e & 63, k = (e >> 6) & 1023, mat = e >> 16;
    const float* W = (mat == 0) ? Wq : ((mat == 1) ? Wk : Wv);
    float scale = (mat == 0) ? 0.0450842298f : 1.0f;   // 2^-5 * log2(e)
    Wt[(size_t)(mat * 64 + col) * 1024 + k] = f2b_rne(W[k * 64 + col] * scale);
}

// ---------------------------------------------------------------------------
// Kernel 2: projections v3 (unchanged from R7).
// ---------------------------------------------------------------------------
template<bool SRC_BF16>
__global__ __launch_bounds__(512) void proj_kernel(
        const void* __restrict__ xsrc, const short* __restrict__ Wt,
        short* __restrict__ QKV) {
    __shared__ short xs[32 * 72];
    __shared__ short wsh[192 * 72];
    int tid = threadIdx.x;
    int w = tid >> 6, l = tid & 63, quad = l >> 4, c16 = l & 15;
    int rt = w >> 2, cg = w & 3;
    int row0 = blockIdx.x * 32;
    short* VpT = QKV + 2 * (size_t)BT * HS;   // tiled [b][kt][64 d][64 key]

    const short* xb = (const short*)xsrc;
    const float* xf = (const float*)xsrc;
    int xrow_b = tid >> 3,  xc8 = (tid & 7) * 8;
    int xrow_f = tid >> 4,  xc4 = (tid & 15) * 4;

    s8v  wreg[3];
    s8v  xreg_b;
    float4 xreg_f;
    #pragma unroll
    for (int i = 0; i < 3; i++) {
        int c = tid + 512 * i;
        wreg[i] = *(const s8v*)(Wt + (size_t)(c >> 3) * 1024 + ((c & 7) * 8));
    }
    if (SRC_BF16) {
        if (tid < 256) xreg_b = *(const s8v*)(xb + (size_t)(row0 + xrow_b) * 1024 + xc8);
    } else {
        xreg_f = *(const float4*)(xf + (size_t)(row0 + xrow_f) * 1024 + xc4);
    }

    f32x4 acc[3] = {};
    for (int ko = 0; ko < NEMBD; ko += 64) {
        #pragma unroll
        for (int i = 0; i < 3; i++) {
            int c = tid + 512 * i;
            *(s8v*)(wsh + (c >> 3) * 72 + ((c & 7) * 8)) = wreg[i];
        }
        if (SRC_BF16) {
            if (tid < 256) *(s8v*)(xs + xrow_b * 72 + xc8) = xreg_b;
        } else {
            union { s4v v; unsigned u[2]; } pkv;
            pkv.u[0] = pk2(xreg_f.x, xreg_f.y);
            pkv.u[1] = pk2(xreg_f.z, xreg_f.w);
            *(s4v*)(xs + xrow_f * 72 + xc4) = pkv.v;
        }
        __syncthreads();
        {
            int kn = (ko + 64 < NEMBD) ? (ko + 64) : 0;
            #pragma unroll
            for (int i = 0; i < 3; i++) {
                int c = tid + 512 * i;
                wreg[i] = *(const s8v*)(Wt + (size_t)(c >> 3) * 1024 + kn + ((c & 7) * 8));
            }
            if (SRC_BF16) {
                if (tid < 256) xreg_b = *(const s8v*)(xb + (size_t)(row0 + xrow_b) * 1024 + kn + xc8);
            } else {
                xreg_f = *(const float4*)(xf + (size_t)(row0 + xrow_f) * 1024 + kn + xc4);
            }
        }
        #pragma unroll
        for (int ks = 0; ks < 2; ks++) {
            s8v a = *(const s8v*)(xs + (rt * 16 + c16) * 72 + ks * 32 + quad * 8);
            #pragma unroll
            for (int j = 0; j < 3; j++) {
                s8v b = *(const s8v*)(wsh + (cg * 48 + j * 16 + c16) * 72 + ks * 32 + quad * 8);
                acc[j] = __builtin_amdgcn_mfma_f32_16x16x32_bf16(a, b, acc[j], 0, 0, 0);
            }
        }
        __syncthreads();
    }
    #pragma unroll
    for (int j = 0; j < 3; j++) {
        int g = cg * 48 + j * 16 + c16;
        int mat = g >> 6, h = g & 63;
        if (mat < 2) {
            #pragma unroll
            for (int r = 0; r < 4; r++) {
                int row = row0 + rt * 16 + quad * 4 + r;
                QKV[(size_t)mat * BT * HS + (size_t)row * HS + h] = f2b_rne(acc[j][r]);
            }
        } else {
            int tg = row0 + rt * 16 + quad * 4;
            int b = tg >> 12, t = tg & 4095;
            size_t base = (((size_t)((b * 64 + (t >> 6)) * 64 + h)) << 6) + (t & 63);
            s4v pv;
            #pragma unroll
            for (int r = 0; r < 4; r++) pv[r] = f2b_rne(acc[j][r]);
            *(s4v*)(VpT + base) = pv;
        }
    }
}

// ---------------------------------------------------------------------------
// Kernel 3: causal flash attention — R16 = R15 with the register cap FIXED.
// R15's __launch_bounds__(1024, 8) set the unified-reg cap to 64 -> compiler
// squeezed arch VGPRs to 32 and spilled ~370MB/dispatch to scratch (WRITE
// 236MB, FETCH 140MB) -- yet occupancy hit 72.7%, CONFIRMING the wide-block
// residency mechanism.  R16 changes exactly one thing vs R15:
//    __launch_bounds__(1024, 4)  -> cap 128, same as R10's, under which this
//    identical tile body has compiled to 64 VGPR for five rounds.
// At 64 VGPR the HW still allows 8 waves/SIMD (occupancy steps at >64), so
// the R15 schedule keeps its residency WITHOUT the spill.
// Everything else identical to R15/R10: 16 waves/block, kt stride 16,
// 512 blocks, big-jt-first dispatch, XCD-affine batch, LDS 72KB (2/CU).
// ---------------------------------------------------------------------------
__global__ __launch_bounds__(1024, 4) void attn_kernel(
        const short* __restrict__ QKV, float* __restrict__ out) {
    __shared__ float smem[18432];   // 72 KB: 16x2 P regions; epilogue overlays
    short* Ps = (short*)smem;

    int tid = threadIdx.x;
    int w = tid >> 6, l = tid & 63, quad = l >> 4, c16 = l & 15;
    int bi = blockIdx.x;
    int b  = (bi & 7) >> 1;                 // XCD-affine batch
    int r8 = bi >> 3;                       // 0..63
    int p  = bi & 1;
    int jt = (r8 < 32) ? (127 - (2 * r8 + p)) : (2 * (r8 - 32) + p);
    int q0 = jt * 32;

    const short* Qp  = QKV;
    const short* Kp  = QKV + (size_t)BT * HS;
    const short* VpT = QKV + 2 * (size_t)BT * HS;   // tiled
    size_t bT = (size_t)b * T_SEQ;

    s8v qf[2][2];
    #pragma unroll
    for (int qt = 0; qt < 2; qt++)
        #pragma unroll
        for (int h = 0; h < 2; h++)
            qf[qt][h] = *(const s8v*)(Qp + (bT + q0 + qt * 16 + c16) * HS + h * 32 + quad * 8);

    f32x4 o[2][4] = {};
    float lsA[2] = {0.f, 0.f}, lsB[2] = {0.f, 0.f};
    int nkt = (q0 >> 6) + 1;
    short* Pw[2] = { Ps + (w * 2) * 1152, Ps + (w * 2 + 1) * 1152 };
    const short* kbase = Kp + (bT + c16) * HS + quad * 8;
    const short* vbase = VpT + (((size_t)((b * 64) * 64 + c16)) << 6) + quad * 8;

    for (int kt = w; kt < nkt; kt += 16) {
        int kb = kt * 64;
        bool last = (kt == nkt - 1);

        // ---- phase 1: issue ALL K fragment loads (8 x b128, one wait) ----
        s8v kf[4][2];
        #pragma unroll
        for (int nt = 0; nt < 4; nt++) {
            const short* kr = kbase + (size_t)(kb + nt * 16) * HS;
            kf[nt][0] = *(const s8v*)kr;
            kf[nt][1] = *(const s8v*)(kr + 32);
        }
        // ---- phase 2: S^T = K * Q^T ----
        f32x4 st[2][4];
        __builtin_amdgcn_s_setprio(1);
        #pragma unroll
        for (int nt = 0; nt < 4; nt++) {
            f32x4 z0 = {0.f, 0.f, 0.f, 0.f}, z1 = {0.f, 0.f, 0.f, 0.f};
            z0 = __builtin_amdgcn_mfma_f32_16x16x32_bf16(kf[nt][0], qf[0][0], z0, 0, 0, 0);
            z0 = __builtin_amdgcn_mfma_f32_16x16x32_bf16(kf[nt][1], qf[0][1], z0, 0, 0, 0);
            z1 = __builtin_amdgcn_mfma_f32_16x16x32_bf16(kf[nt][0], qf[1][0], z1, 0, 0, 0);
            z1 = __builtin_amdgcn_mfma_f32_16x16x32_bf16(kf[nt][1], qf[1][1], z1, 0, 0, 0);
            st[0][nt] = z0; st[1][nt] = z1;
        }
        __builtin_amdgcn_s_setprio(0);
        // ---- phase 3: issue ALL V fragment loads (hidden by softmax) ----
        s8v vf[4][2];
        #pragma unroll
        for (int nt = 0; nt < 4; nt++) {
            const short* vr = vbase + (((size_t)(kb + nt * 16)) << 6);
            vf[nt][0] = *(const s8v*)vr;
            vf[nt][1] = *(const s8v*)(vr + 32);
        }
        // ---- phase 4: exp2, diag mask, lsum, pack P -> LDS ----
        #pragma unroll
        for (int qt = 0; qt < 2; qt++) {
            int qrow = q0 + qt * 16 + c16;
            #pragma unroll
            for (int nt = 0; nt < 4; nt++) {
                float pr[4];
                #pragma unroll
                for (int rr = 0; rr < 4; rr++) {
                    float v = st[qt][nt][rr];
                    if (last && (kb + nt * 16 + quad * 4 + rr > qrow)) v = -30000.f;
                    pr[rr] = __builtin_amdgcn_exp2f(v);
                }
                lsA[qt] += pr[0] + pr[1];
                lsB[qt] += pr[2] + pr[3];
                union { s4v v; unsigned u[2]; } pkv;
                pkv.u[0] = pk2(pr[0], pr[1]); pkv.u[1] = pk2(pr[2], pr[3]);
                *(s4v*)(Pw[qt] + c16 * 72 + nt * 16 + quad * 4) = pkv.v;
            }
        }
        // ---- phase 5: P A-frags from LDS; phase 6: PV MFMAs ----
        s8v pa[2][2];
        #pragma unroll
        for (int qt = 0; qt < 2; qt++) {
            pa[qt][0] = *(const s8v*)(Pw[qt] + c16 * 72 + quad * 8);
            pa[qt][1] = *(const s8v*)(Pw[qt] + c16 * 72 + quad * 8 + 32);
        }
        __builtin_amdgcn_s_setprio(1);
        #pragma unroll
        for (int nt = 0; nt < 4; nt++)
            #pragma unroll
            for (int qt = 0; qt < 2; qt++) {
                o[qt][nt] = __builtin_amdgcn_mfma_f32_16x16x32_bf16(pa[qt][0], vf[nt][0], o[qt][nt], 0, 0, 0);
                o[qt][nt] = __builtin_amdgcn_mfma_f32_16x16x32_bf16(pa[qt][1], vf[nt][1], o[qt][nt], 0, 0, 0);
            }
        __builtin_amdgcn_s_setprio(0);
    }

    float lsum[2] = { lsA[0] + lsB[0], lsA[1] + lsB[1] };
    #pragma unroll
    for (int qt = 0; qt < 2; qt++) {
        lsum[qt] += __shfl_xor(lsum[qt], 16);
        lsum[qt] += __shfl_xor(lsum[qt], 32);
    }

    // two-phase per-lane merge across 16 waves (R5 structure, widened)
    #pragma unroll
    for (int qt = 0; qt < 2; qt++) {
        __syncthreads();
        #pragma unroll
        for (int nt = 0; nt < 4; nt++)
            *(f32x4*)(smem + ((w * 4 + nt) * 64 + l) * 4) = o[qt][nt];
        if (l < 16) smem[16384 + w * 16 + l] = lsum[qt];
        __syncthreads();
        if (w < 4) {
            f32x4 os = {0.f, 0.f, 0.f, 0.f}, ls = {0.f, 0.f, 0.f, 0.f};
            #pragma unroll
            for (int s = 0; s < 16; s++) {
                os += *(const f32x4*)(smem + ((s * 4 + w) * 64 + l) * 4);
                ls += *(const f32x4*)(smem + 16384 + s * 16 + quad * 4);
            }
            #pragma unroll
            for (int rr = 0; rr < 4; rr++)
                out[(bT + q0 + qt * 16 + quad * 4 + rr) * HS + w * 16 + c16] = os[rr] / ls[rr];
        }
    }
}

// ---------------------------------------------------------------------------
extern "C" void kernel_launch(void* const* d_in, const int* in_sizes, int n_in,
                              void* d_out, int out_size, void* d_ws, size_t ws_size,
                              hipStream_t stream) {
    const float* x  = (const float*)d_in[0];
    const float* Wq = (const float*)d_in[1];
    const float* Wk = (const float*)d_in[2];
    const float* Wv = (const float*)d_in[3];
    float* out = (float*)d_out;

    short* QKV = (short*)d_ws;
    short* Wt  = QKV + (size_t)3 * BT * HS;
    short* xb  = Wt + (size_t)192 * 1024;
    size_t need = ((size_t)3 * BT * HS + (size_t)192 * 1024 + (size_t)BT * NEMBD) * 2;

    wtrans_kernel<<<768, 256, 0, stream>>>(Wq, Wk, Wv, Wt);
    if (ws_size >= need) {
        xcast_kernel<<<4096, 256, 0, stream>>>(x, xb);
        proj_kernel<true><<<BT / 32, 512, 0, stream>>>(xb, Wt, QKV);
    } else {
        xtouch_kernel<<<2048, 256, 0, stream>>>(x, (float*)d_ws);
        proj_kernel<false><<<BT / 32, 512, 0, stream>>>(x, Wt, QKV);
    }
    attn_kernel<<<512, 1024, 0, stream>>>(QKV, out);
}